// Round 2
// baseline (2266.350 us; speedup 1.0000x reference)
//
#include <hip/hip_runtime.h>
#include <hip/hip_bf16.h>

#define IN_F   4096
#define OUT_F  11008
#define MROWS  4096   // 2*2048 rows of x
#define BM     128
#define BN     128
#define BK     64
#define LDK    72     // padded LDS row stride (elements) -> 2-way bank aliasing only

typedef __bf16 bf16x8 __attribute__((ext_vector_type(8)));
typedef float  f32x4  __attribute__((ext_vector_type(4)));

// ---------------------------------------------------------------------------
// Dequantize W: (q * 2/7 - 1) * scale, zeroed where mask != 0  ->  bf16 [OUT_F][IN_F]
// ---------------------------------------------------------------------------
__global__ __launch_bounds__(256) void k_dequant(const int* __restrict__ q,
                                                 const int* __restrict__ mask,
                                                 const float* __restrict__ scales,
                                                 __hip_bfloat16* __restrict__ Wb)
{
    const long long t    = (long long)blockIdx.x * 256 + threadIdx.x;
    const long long base = t * 8;
    const int   g = (int)(base >> 6);
    const float s = scales[g];
    const int4 q0 = *(const int4*)(q + base);
    const int4 q1 = *(const int4*)(q + base + 4);
    const int4 m0 = *(const int4*)(mask + base);
    const int4 m1 = *(const int4*)(mask + base + 4);
    const float c = 2.0f / 7.0f;
    int qa[8] = {q0.x, q0.y, q0.z, q0.w, q1.x, q1.y, q1.z, q1.w};
    int ma[8] = {m0.x, m0.y, m0.z, m0.w, m1.x, m1.y, m1.z, m1.w};
    union { int4 v; __hip_bfloat16 h[8]; } u;
#pragma unroll
    for (int j = 0; j < 8; ++j) {
        float w = ma[j] ? 0.0f : ((float)qa[j] * c - 1.0f) * s;
        u.h[j] = __float2bfloat16(w);
    }
    *(int4*)(Wb + base) = u.v;
}

// ---------------------------------------------------------------------------
// Convert x fp32 -> bf16, 8 elems/thread
// ---------------------------------------------------------------------------
__global__ __launch_bounds__(256) void k_cvt_x(const float* __restrict__ x,
                                               __hip_bfloat16* __restrict__ xb)
{
    const long long t    = (long long)blockIdx.x * 256 + threadIdx.x;
    const long long base = t * 8;
    const float4 a = *(const float4*)(x + base);
    const float4 b = *(const float4*)(x + base + 4);
    float f[8] = {a.x, a.y, a.z, a.w, b.x, b.y, b.z, b.w};
    union { int4 v; __hip_bfloat16 h[8]; } u;
#pragma unroll
    for (int j = 0; j < 8; ++j) u.h[j] = __float2bfloat16(f[j]);
    *(int4*)(xb + base) = u.v;
}

// ---------------------------------------------------------------------------
// bf16 MFMA GEMM: C[m][n] = sum_k A[m][k] * B[n][k] + bias[n], C stored fp32
// A = xb [MROWS][IN_F], B = Wb [OUT_F][IN_F] (both K-contiguous)
// 128x128 tile, BK=64, 4 waves (2x2), each wave 4x4 frags of 16x16x32.
// Verified layouts (learn_hip m89/m91):
//   A-op: m = lane&15, k = (lane>>4)*8 + j
//   B-op: n = lane&15, k = (lane>>4)*8 + j
//   C/D : n = lane&15, m = (lane>>4)*4 + reg
// ---------------------------------------------------------------------------
__global__ __launch_bounds__(256) void k_gemm(const __hip_bfloat16* __restrict__ A,
                                              const __hip_bfloat16* __restrict__ B,
                                              const float* __restrict__ bias,
                                              float* __restrict__ C)
{
    __shared__ __align__(16) __hip_bfloat16 As[BM * LDK];
    __shared__ __align__(16) __hip_bfloat16 Bs[BN * LDK];

    const int tid  = threadIdx.x;
    const int lane = tid & 63;
    const int wave = tid >> 6;
    const int wm   = wave >> 1;       // 0..1
    const int wn   = wave & 1;        // 0..1
    const int quad = lane >> 4;       // 0..3
    const int lr   = lane & 15;
    const int bm   = blockIdx.y;
    const int bn   = blockIdx.x;

    const __hip_bfloat16* Ablk = A + (size_t)bm * BM * IN_F;
    const __hip_bfloat16* Bblk = B + (size_t)bn * BN * IN_F;

    const int srow = tid >> 3;        // + it*32
    const int scol = (tid & 7) * 8;

    f32x4 acc[4][4];
#pragma unroll
    for (int i = 0; i < 4; ++i)
#pragma unroll
        for (int j = 0; j < 4; ++j)
            acc[i][j] = (f32x4){0.f, 0.f, 0.f, 0.f};

    for (int k0 = 0; k0 < IN_F; k0 += BK) {
        int4 ra[4], rb[4];
#pragma unroll
        for (int it = 0; it < 4; ++it) {
            const int row = it * 32 + srow;
            ra[it] = *(const int4*)(Ablk + (size_t)row * IN_F + k0 + scol);
            rb[it] = *(const int4*)(Bblk + (size_t)row * IN_F + k0 + scol);
        }
        __syncthreads();
#pragma unroll
        for (int it = 0; it < 4; ++it) {
            const int row = it * 32 + srow;
            *(int4*)(&As[row * LDK + scol]) = ra[it];
            *(int4*)(&Bs[row * LDK + scol]) = rb[it];
        }
        __syncthreads();
#pragma unroll
        for (int kk = 0; kk < BK; kk += 32) {
            bf16x8 af[4], bg[4];
#pragma unroll
            for (int i = 0; i < 4; ++i) {
                af[i] = *(const bf16x8*)(&As[(wm * 64 + i * 16 + lr) * LDK + kk + quad * 8]);
                bg[i] = *(const bf16x8*)(&Bs[(wn * 64 + i * 16 + lr) * LDK + kk + quad * 8]);
            }
#pragma unroll
            for (int i = 0; i < 4; ++i)
#pragma unroll
                for (int j = 0; j < 4; ++j)
                    acc[i][j] = __builtin_amdgcn_mfma_f32_16x16x32_bf16(af[i], bg[j], acc[i][j], 0, 0, 0);
        }
    }

    // epilogue: bias add + fp32 store (reference output dtype is float32)
#pragma unroll
    for (int j = 0; j < 4; ++j) {
        const int gn = bn * BN + wn * 64 + j * 16 + lr;
        const float bv = bias[gn];
#pragma unroll
        for (int i = 0; i < 4; ++i) {
            const int gm0 = bm * BM + wm * 64 + i * 16 + quad * 4;
#pragma unroll
            for (int r = 0; r < 4; ++r) {
                C[(size_t)(gm0 + r) * OUT_F + gn] = acc[i][j][r] + bv;
            }
        }
    }
}

extern "C" void kernel_launch(void* const* d_in, const int* in_sizes, int n_in,
                              void* d_out, int out_size, void* d_ws, size_t ws_size,
                              hipStream_t stream)
{
    const float* x      = (const float*)d_in[0];
    const int*   q      = (const int*)d_in[1];
    const float* scales = (const float*)d_in[2];
    const int*   mask   = (const int*)d_in[3];
    const float* bias   = (const float*)d_in[4];
    float* out          = (float*)d_out;

    __hip_bfloat16* xb = (__hip_bfloat16*)d_ws;                 // 4096*4096 bf16 = 33.5 MB
    __hip_bfloat16* Wb = xb + (size_t)MROWS * IN_F;             // 11008*4096 bf16 = 90.2 MB

    k_cvt_x<<<(MROWS * IN_F) / (256 * 8), 256, 0, stream>>>(x, xb);
    k_dequant<<<(OUT_F * IN_F) / (256 * 8), 256, 0, stream>>>(q, mask, scales, Wb);

    dim3 grid(OUT_F / BN, MROWS / BM);   // (86, 32)
    k_gemm<<<grid, 256, 0, stream>>>(xb, Wb, bias, out);
}

// Round 3
// 1046.024 us; speedup vs baseline: 2.1666x; 2.1666x over previous
//
#include <hip/hip_runtime.h>
#include <hip/hip_bf16.h>

#define IN_F   4096
#define OUT_F  11008
#define MROWS  4096   // 2*2048 rows of x
#define BM     128
#define BN     128
#define BK     64

typedef __bf16 bf16x8 __attribute__((ext_vector_type(8)));
typedef float  f32x4  __attribute__((ext_vector_type(4)));

// ---------------------------------------------------------------------------
// Dequantize W: (q * 2/7 - 1) * scale, zeroed where mask != 0  ->  bf16 [OUT_F][IN_F]
// ---------------------------------------------------------------------------
__global__ __launch_bounds__(256) void k_dequant(const int* __restrict__ q,
                                                 const int* __restrict__ mask,
                                                 const float* __restrict__ scales,
                                                 __hip_bfloat16* __restrict__ Wb)
{
    const long long t    = (long long)blockIdx.x * 256 + threadIdx.x;
    const long long base = t * 8;
    const int   g = (int)(base >> 6);
    const float s = scales[g];
    const int4 q0 = *(const int4*)(q + base);
    const int4 q1 = *(const int4*)(q + base + 4);
    const int4 m0 = *(const int4*)(mask + base);
    const int4 m1 = *(const int4*)(mask + base + 4);
    const float c = 2.0f / 7.0f;
    int qa[8] = {q0.x, q0.y, q0.z, q0.w, q1.x, q1.y, q1.z, q1.w};
    int ma[8] = {m0.x, m0.y, m0.z, m0.w, m1.x, m1.y, m1.z, m1.w};
    union { int4 v; __hip_bfloat16 h[8]; } u;
#pragma unroll
    for (int j = 0; j < 8; ++j) {
        float w = ma[j] ? 0.0f : ((float)qa[j] * c - 1.0f) * s;
        u.h[j] = __float2bfloat16(w);
    }
    *(int4*)(Wb + base) = u.v;
}

// ---------------------------------------------------------------------------
// Convert x fp32 -> bf16, 8 elems/thread
// ---------------------------------------------------------------------------
__global__ __launch_bounds__(256) void k_cvt_x(const float* __restrict__ x,
                                               __hip_bfloat16* __restrict__ xb)
{
    const long long t    = (long long)blockIdx.x * 256 + threadIdx.x;
    const long long base = t * 8;
    const float4 a = *(const float4*)(x + base);
    const float4 b = *(const float4*)(x + base + 4);
    float f[8] = {a.x, a.y, a.z, a.w, b.x, b.y, b.z, b.w};
    union { int4 v; __hip_bfloat16 h[8]; } u;
#pragma unroll
    for (int j = 0; j < 8; ++j) u.h[j] = __float2bfloat16(f[j]);
    *(int4*)(xb + base) = u.v;
}

// ---------------------------------------------------------------------------
// async global->LDS, 16 B per lane, wave-uniform LDS base (HW adds lane*16)
// ---------------------------------------------------------------------------
__device__ __forceinline__ void gl_lds16(const __hip_bfloat16* g, __hip_bfloat16* l)
{
    __builtin_amdgcn_global_load_lds(
        (const __attribute__((address_space(1))) void*)g,
        (__attribute__((address_space(3))) void*)l,
        16, 0, 0);
}

// ---------------------------------------------------------------------------
// bf16 MFMA GEMM (m97 structure): C[s][o] = sum_k x[s][k] * W[o][k] + bias[o]
// Role-swapped MFMA: A-operand = W frag (m = o), B-operand = x frag (n = s)
//   => C/D layout: n = s = lane&15, m = o = quad*4 + reg  -> float4 stores.
// 128x128 tile, BK=64, unpadded LDS (required by global_load_lds lane order).
// ---------------------------------------------------------------------------
__global__ __launch_bounds__(256) void k_gemm(const __hip_bfloat16* __restrict__ A,
                                              const __hip_bfloat16* __restrict__ B,
                                              const float* __restrict__ bias,
                                              float* __restrict__ C)
{
    __shared__ __align__(16) __hip_bfloat16 As[BM * BK];   // x tile, 16 KB
    __shared__ __align__(16) __hip_bfloat16 Bs[BN * BK];   // W tile, 16 KB

    const int tid  = threadIdx.x;
    const int lane = tid & 63;
    const int wave = tid >> 6;
    const int wm   = wave >> 1;       // 0..1  (s half)
    const int wn   = wave & 1;        // 0..1  (o half)
    const int quad = lane >> 4;       // 0..3
    const int lr   = lane & 15;
    const int bm   = blockIdx.x;      // M fastest: resident blocks share B panels
    const int bn   = blockIdx.y;

    const __hip_bfloat16* Ablk = A + (size_t)bm * BM * IN_F;
    const __hip_bfloat16* Bblk = B + (size_t)bn * BN * IN_F;

    // staging geometry: chunk c = wave*4+t covers rows c*8..c*8+7 (1 KB), lane
    // l supplies row c*8 + l/8, cols (l%8)*8 .. +8  (16 B) — matches HW lane order.
    const int lrow = lane >> 3;
    const int lcol = (lane & 7) * 8;

    f32x4 acc[4][4];
#pragma unroll
    for (int i = 0; i < 4; ++i)
#pragma unroll
        for (int j = 0; j < 4; ++j)
            acc[i][j] = (f32x4){0.f, 0.f, 0.f, 0.f};

    for (int k0 = 0; k0 < IN_F; k0 += BK) {
        __syncthreads();   // LDS from previous iter fully consumed
#pragma unroll
        for (int t = 0; t < 4; ++t) {
            const int c   = wave * 4 + t;          // 0..15
            const int row = c * 8 + lrow;
            gl_lds16(Ablk + (size_t)row * IN_F + k0 + lcol, &As[c * 512]);
            gl_lds16(Bblk + (size_t)row * IN_F + k0 + lcol, &Bs[c * 512]);
        }
        __syncthreads();   // drains vmcnt -> staged tiles visible
#pragma unroll
        for (int kk = 0; kk < BK; kk += 32) {
            bf16x8 wf[4], xf[4];
#pragma unroll
            for (int i = 0; i < 4; ++i) {
                wf[i] = *(const bf16x8*)(&Bs[(wn * 64 + i * 16 + lr) * BK + kk + quad * 8]);
                xf[i] = *(const bf16x8*)(&As[(wm * 64 + i * 16 + lr) * BK + kk + quad * 8]);
            }
#pragma unroll
            for (int i = 0; i < 4; ++i)
#pragma unroll
                for (int j = 0; j < 4; ++j)
                    acc[i][j] = __builtin_amdgcn_mfma_f32_16x16x32_bf16(wf[i], xf[j], acc[i][j], 0, 0, 0);
        }
    }

    // epilogue: lane holds 4 consecutive o per frag -> float4 store + float4 bias
#pragma unroll
    for (int i = 0; i < 4; ++i) {
        const int o = bn * BN + wn * 64 + i * 16 + quad * 4;
        const float4 bv = *(const float4*)(bias + o);
#pragma unroll
        for (int j = 0; j < 4; ++j) {
            const int s = bm * BM + wm * 64 + j * 16 + lr;
            float4 v;
            v.x = acc[i][j][0] + bv.x;
            v.y = acc[i][j][1] + bv.y;
            v.z = acc[i][j][2] + bv.z;
            v.w = acc[i][j][3] + bv.w;
            *(float4*)(C + (size_t)s * OUT_F + o) = v;
        }
    }
}

extern "C" void kernel_launch(void* const* d_in, const int* in_sizes, int n_in,
                              void* d_out, int out_size, void* d_ws, size_t ws_size,
                              hipStream_t stream)
{
    const float* x      = (const float*)d_in[0];
    const int*   q      = (const int*)d_in[1];
    const float* scales = (const float*)d_in[2];
    const int*   mask   = (const int*)d_in[3];
    const float* bias   = (const float*)d_in[4];
    float* out          = (float*)d_out;

    __hip_bfloat16* xb = (__hip_bfloat16*)d_ws;                 // 33.5 MB
    __hip_bfloat16* Wb = xb + (size_t)MROWS * IN_F;             // 90.2 MB

    k_cvt_x<<<(MROWS * IN_F) / (256 * 8), 256, 0, stream>>>(x, xb);
    k_dequant<<<(OUT_F * IN_F) / (256 * 8), 256, 0, stream>>>(q, mask, scales, Wb);

    dim3 grid(MROWS / BM, OUT_F / BN);   // (32, 86), M fastest
    k_gemm<<<grid, 256, 0, stream>>>(xb, Wb, bias, out);
}

// Round 4
// 999.213 us; speedup vs baseline: 2.2681x; 1.0468x over previous
//
#include <hip/hip_runtime.h>
#include <hip/hip_bf16.h>

#define IN_F   4096
#define OUT_F  11008
#define MROWS  4096   // 2*2048 rows of x
#define BM     128
#define BN     128
#define BK     64
#define CVT_BLOCKS ((MROWS * IN_F) / (256 * 8))      // 8192
#define DEQ_BLOCKS ((OUT_F * IN_F) / (256 * 8))      // 22016

typedef __bf16 bf16x8 __attribute__((ext_vector_type(8)));
typedef float  f32x4  __attribute__((ext_vector_type(4)));

// ---------------------------------------------------------------------------
// Fused prep: blocks [0,CVT_BLOCKS) convert x fp32->bf16; the rest dequantize
// W: (q * 2/7 - 1) * scale, zeroed where mask != 0  ->  bf16 [OUT_F][IN_F].
// Block-uniform branch, both halves BW-bound; fusing lets them overlap.
// ---------------------------------------------------------------------------
__global__ __launch_bounds__(256) void k_prep(const float* __restrict__ x,
                                              const int* __restrict__ q,
                                              const int* __restrict__ mask,
                                              const float* __restrict__ scales,
                                              __hip_bfloat16* __restrict__ xb,
                                              __hip_bfloat16* __restrict__ Wb)
{
    if (blockIdx.x < CVT_BLOCKS) {
        const long long t    = (long long)blockIdx.x * 256 + threadIdx.x;
        const long long base = t * 8;
        const float4 a = *(const float4*)(x + base);
        const float4 b = *(const float4*)(x + base + 4);
        float f[8] = {a.x, a.y, a.z, a.w, b.x, b.y, b.z, b.w};
        union { int4 v; __hip_bfloat16 h[8]; } u;
#pragma unroll
        for (int j = 0; j < 8; ++j) u.h[j] = __float2bfloat16(f[j]);
        *(int4*)(xb + base) = u.v;
    } else {
        const long long t    = (long long)(blockIdx.x - CVT_BLOCKS) * 256 + threadIdx.x;
        const long long base = t * 8;
        const int   g = (int)(base >> 6);
        const float s = scales[g];
        const int4 q0 = *(const int4*)(q + base);
        const int4 q1 = *(const int4*)(q + base + 4);
        const int4 m0 = *(const int4*)(mask + base);
        const int4 m1 = *(const int4*)(mask + base + 4);
        const float c = 2.0f / 7.0f;
        int qa[8] = {q0.x, q0.y, q0.z, q0.w, q1.x, q1.y, q1.z, q1.w};
        int ma[8] = {m0.x, m0.y, m0.z, m0.w, m1.x, m1.y, m1.z, m1.w};
        union { int4 v; __hip_bfloat16 h[8]; } u;
#pragma unroll
        for (int j = 0; j < 8; ++j) {
            float w = ma[j] ? 0.0f : ((float)qa[j] * c - 1.0f) * s;
            u.h[j] = __float2bfloat16(w);
        }
        *(int4*)(Wb + base) = u.v;
    }
}

// ---------------------------------------------------------------------------
// async global->LDS, 16 B per lane, wave-uniform LDS base (HW adds lane*16)
// ---------------------------------------------------------------------------
__device__ __forceinline__ void gl_lds16(const __hip_bfloat16* g, __hip_bfloat16* l)
{
    __builtin_amdgcn_global_load_lds(
        (const __attribute__((address_space(1))) void*)g,
        (__attribute__((address_space(3))) void*)l,
        16, 0, 0);
}

// ---------------------------------------------------------------------------
// bf16 MFMA GEMM (m97 structure + XOR-swizzled LDS):
//   C[s][o] = sum_k x[s][k] * W[o][k] + bias[o]
// Role-swapped MFMA: A-op = W frag (m = o), B-op = x frag (n = s)
//   => C/D: n = s = lane&15, m = o = quad*4 + reg  -> float4 stores.
// LDS swizzle: logical col-block cb of row stored at physical cb ^ (row&7).
//   Write side: lane l fetches global col-block (l&7)^(l>>3) (same 128 B
//   segment per 8-lane group -> coalescing intact; DMA dest order unchanged).
//   Read side: quad lanes sweep all 32 banks at 2-way aliasing (free, m136)
//   instead of the unswizzled 8-way conflict (was 33% of cycles in R3).
// ---------------------------------------------------------------------------
__global__ __launch_bounds__(256) void k_gemm(const __hip_bfloat16* __restrict__ A,
                                              const __hip_bfloat16* __restrict__ B,
                                              const float* __restrict__ bias,
                                              float* __restrict__ C)
{
    __shared__ __align__(16) __hip_bfloat16 As[BM * BK];   // x tile, 16 KB
    __shared__ __align__(16) __hip_bfloat16 Bs[BN * BK];   // W tile, 16 KB

    const int tid  = threadIdx.x;
    const int lane = tid & 63;
    const int wave = tid >> 6;
    const int wm   = wave >> 1;       // 0..1  (s half)
    const int wn   = wave & 1;        // 0..1  (o half)
    const int quad = lane >> 4;       // 0..3
    const int lr   = lane & 15;
    const int swr  = lr & 7;          // read-side swizzle key (= row&7 of frag row)
    const int bm   = blockIdx.x;      // M fastest: resident blocks share B panels
    const int bn   = blockIdx.y;

    const __hip_bfloat16* Ablk = A + (size_t)bm * BM * IN_F;
    const __hip_bfloat16* Bblk = B + (size_t)bn * BN * IN_F;

    // staging: chunk c = wave*4+t covers rows c*8..c*8+7; lane l supplies
    // row c*8 + l/8, logical col-block (l&7)^(l/8)  (XOR swizzle).
    const int lrow = lane >> 3;
    const int lcol = ((lane & 7) ^ lrow) * 8;

    f32x4 acc[4][4];
#pragma unroll
    for (int i = 0; i < 4; ++i)
#pragma unroll
        for (int j = 0; j < 4; ++j)
            acc[i][j] = (f32x4){0.f, 0.f, 0.f, 0.f};

    for (int k0 = 0; k0 < IN_F; k0 += BK) {
        __syncthreads();   // LDS from previous iter fully consumed
#pragma unroll
        for (int t = 0; t < 4; ++t) {
            const int c   = wave * 4 + t;          // 0..15
            const int row = c * 8 + lrow;
            gl_lds16(Ablk + (size_t)row * IN_F + k0 + lcol, &As[c * 512]);
            gl_lds16(Bblk + (size_t)row * IN_F + k0 + lcol, &Bs[c * 512]);
        }
        __syncthreads();   // drains vmcnt -> staged tiles visible
#pragma unroll
        for (int kk = 0; kk < BK; kk += 32) {
            bf16x8 wf[4], xf[4];
#pragma unroll
            for (int i = 0; i < 4; ++i) {
                const int pcb = ((quad + (kk >> 3)) ^ swr) << 3;   // physical col
                wf[i] = *(const bf16x8*)(&Bs[(wn * 64 + i * 16 + lr) * BK + pcb]);
                xf[i] = *(const bf16x8*)(&As[(wm * 64 + i * 16 + lr) * BK + pcb]);
            }
#pragma unroll
            for (int i = 0; i < 4; ++i)
#pragma unroll
                for (int j = 0; j < 4; ++j)
                    acc[i][j] = __builtin_amdgcn_mfma_f32_16x16x32_bf16(wf[i], xf[j], acc[i][j], 0, 0, 0);
        }
    }

    // epilogue: lane holds 4 consecutive o per frag -> float4 store + float4 bias
#pragma unroll
    for (int i = 0; i < 4; ++i) {
        const int o = bn * BN + wn * 64 + i * 16 + quad * 4;
        const float4 bv = *(const float4*)(bias + o);
#pragma unroll
        for (int j = 0; j < 4; ++j) {
            const int s = bm * BM + wm * 64 + j * 16 + lr;
            float4 v;
            v.x = acc[i][j][0] + bv.x;
            v.y = acc[i][j][1] + bv.y;
            v.z = acc[i][j][2] + bv.z;
            v.w = acc[i][j][3] + bv.w;
            *(float4*)(C + (size_t)s * OUT_F + o) = v;
        }
    }
}

extern "C" void kernel_launch(void* const* d_in, const int* in_sizes, int n_in,
                              void* d_out, int out_size, void* d_ws, size_t ws_size,
                              hipStream_t stream)
{
    const float* x      = (const float*)d_in[0];
    const int*   q      = (const int*)d_in[1];
    const float* scales = (const float*)d_in[2];
    const int*   mask   = (const int*)d_in[3];
    const float* bias   = (const float*)d_in[4];
    float* out          = (float*)d_out;

    __hip_bfloat16* xb = (__hip_bfloat16*)d_ws;                 // 33.5 MB
    __hip_bfloat16* Wb = xb + (size_t)MROWS * IN_F;             // 90.2 MB

    k_prep<<<CVT_BLOCKS + DEQ_BLOCKS, 256, 0, stream>>>(x, q, mask, scales, xb, Wb);

    dim3 grid(MROWS / BM, OUT_F / BN);   // (32, 86), M fastest
    k_gemm<<<grid, 256, 0, stream>>>(xb, Wb, bias, out);
}